// Round 5
// baseline (10975.304 us; speedup 1.0000x reference)
//
#include <hip/hip_runtime.h>

#define Tn 512
#define Hn 512
#define HS 65536           // u32 elements per h ring slot (128*512)
#define NBLK 256

typedef __attribute__((ext_vector_type(8))) short s8v;     // 8 bf16 (MFMA A/B frag)
typedef __attribute__((ext_vector_type(4))) float f4v;     // MFMA acc
typedef __attribute__((ext_vector_type(4))) unsigned u4v;

__device__ __forceinline__ unsigned short f2bf(float f) {  // RNE
  unsigned u = __float_as_uint(f);
  u = u + 0x7fffu + ((u >> 16) & 1u);
  return (unsigned short)(u >> 16);
}
__device__ __forceinline__ float bf2f(unsigned short s) {
  return __uint_as_float(((unsigned)s) << 16);
}
__device__ __forceinline__ float sigm(float v) { return 1.f / (1.f + __expf(-v)); }
__device__ __forceinline__ float tanh_f(float v) {
  v = fminf(fmaxf(v, -15.f), 15.f);
  float e = __expf(2.f * v);
  return (e - 1.f) / (e + 1.f);
}
__device__ __forceinline__ f4v mfma3(s8v ah, s8v al, s8v wh, s8v wl, f4v c) {
  c = __builtin_amdgcn_mfma_f32_16x16x32_bf16(ah, wh, c, 0, 0, 0);
  c = __builtin_amdgcn_mfma_f32_16x16x32_bf16(al, wh, c, 0, 0, 0);
  c = __builtin_amdgcn_mfma_f32_16x16x32_bf16(ah, wl, c, 0, 0, 0);
  return c;
}

// ---------------- persistent fused 2-layer GRU, group-decoupled sync ----------------
// 256 blocks. g = bid&7 = mq*2+layer (group <-> one XCD); jg = bid>>3 (16 cols).
// Group (layer,mq) = 32 jg-blocks; they exchange h only among themselves ->
// 32-block group barrier (8 independent counters). Layer0-mq -> layer1-mq handoff
// via h1 depth-4 ring + progress counters (back-pressure: layer0 <= 3 ahead).
// h packed as u32 = (bf16_hi << 16) | bf16_lo: full-line stores, no false sharing.
// 4 waves/block: kh = wv&1 (K-half), hs = wv>>1 (0: input-side GEMM, 1: h GEMM).
// Weights bf16 hi/lo in VGPRs (192/wave), loaded once. x register-prefetched.
__global__ __launch_bounds__(256, 1) void gru_fused(
    const float* __restrict__ x,
    const float* __restrict__ Wih0, const float* __restrict__ Whh0,
    const float* __restrict__ bih0, const float* __restrict__ bhh0,
    const float* __restrict__ Wih1, const float* __restrict__ Whh1,
    const float* __restrict__ bih1, const float* __restrict__ bhh1,
    unsigned* __restrict__ gcnt,   // [8] stride 32 u32
    unsigned* __restrict__ l0prog, // [4] stride 32 u32
    unsigned* __restrict__ l1prog, // [4] stride 32 u32
    unsigned* __restrict__ h1ring, // 4 slots x 65536 u32
    unsigned* __restrict__ h2ring, // 2 slots x 65536 u32
    float* __restrict__ h2fin) {
  __shared__ float part[3][64][25];   // partial-acc handoff (stride 25: conflict-free)

  const int tid = threadIdx.x, lane = tid & 63, wv = tid >> 6;
  const int kh = wv & 1, hs = wv >> 1;
  const int colr = lane & 15, kg = lane >> 4;

  const int bid = blockIdx.x;
  const int g = bid & 7;
  const int layer = g & 1;
  const int mq = g >> 1;                   // row quarter (32 rows)
  const int jg = bid >> 3;                 // 0..31 column group
  const int col = jg * 16 + colr;

  // ---- load weight fragments (this wave's matrix + K-half) ----
  // B-frag: lane holds W[col][k = kh*256 + ks*32 + kg*8 + e]
  const float* W = (layer == 0) ? (hs ? Whh0 : Wih0) : (hs ? Whh1 : Wih1);
  s8v wh[3][8], wl[3][8];
#pragma unroll
  for (int gg = 0; gg < 3; ++gg) {
    const float* wrow = W + (size_t)(gg * Hn + col) * Hn + kh * 256 + kg * 8;
#pragma unroll
    for (int ks = 0; ks < 8; ++ks) {
#pragma unroll
      for (int e = 0; e < 8; ++e) {
        float v = wrow[ks * 32 + e];
        unsigned short hi = f2bf(v);
        wh[gg][ks][e] = (short)hi;
        wl[gg][ks][e] = (short)f2bf(v - bf2f(hi));
      }
    }
  }

  // biases: only the epilogue wave (hs==1, kh==0)
  float brz = 0, bzz = 0, bin = 0, bhn = 0;
  if (hs == 1 && kh == 0) {
    const float* bi = layer ? bih1 : bih0;
    const float* bb = layer ? bhh1 : bhh0;
    brz = bi[col] + bb[col];
    bzz = bi[Hn + col] + bb[Hn + col];
    bin = bi[2 * Hn + col];
    bhn = bb[2 * Hn + col];
  }

  const bool is_xw = (layer == 0 && hs == 0);   // x-prefetching wave

  // x prefetch registers: 2 mt x 8 ks x 2 float4
  float4 xp[2][8][2];
  if (is_xw) {
#pragma unroll
    for (int mt = 0; mt < 2; ++mt) {
      const int rowA = mq * 32 + mt * 16 + colr;
      const float* xq = x + ((size_t)rowA * Tn) * 512 + kh * 256 + kg * 8;  // t = 0
#pragma unroll
      for (int ks = 0; ks < 8; ++ks) {
        xp[mt][ks][0] = *(const float4*)(xq + ks * 32);
        xp[mt][ks][1] = *(const float4*)(xq + ks * 32 + 4);
      }
    }
  }

  unsigned* const mygc = gcnt + g * 32;
  unsigned* const myprog = (layer ? l1prog : l0prog) + mq * 32;
  const unsigned* const peerprog = (layer ? l0prog : l1prog) + mq * 32;

  float hown[2][4] = {{0.f, 0.f, 0.f, 0.f}, {0.f, 0.f, 0.f, 0.f}};

  for (int t = 0; t < Tn; ++t) {
    f4v acc[2][3];
#pragma unroll
    for (int mt = 0; mt < 2; ++mt)
#pragma unroll
      for (int gg = 0; gg < 3; ++gg) acc[mt][gg] = (f4v){0.f, 0.f, 0.f, 0.f};

    if (is_xw) {
      // ---- x-input GEMM from prefetched registers; hi/lo by truncation ----
#pragma unroll
      for (int mt = 0; mt < 2; ++mt) {
#pragma unroll
        for (int ks = 0; ks < 8; ++ks) {
          float v[8];
          v[0] = xp[mt][ks][0].x; v[1] = xp[mt][ks][0].y;
          v[2] = xp[mt][ks][0].z; v[3] = xp[mt][ks][0].w;
          v[4] = xp[mt][ks][1].x; v[5] = xp[mt][ks][1].y;
          v[6] = xp[mt][ks][1].z; v[7] = xp[mt][ks][1].w;
          u4v au, lu;
#pragma unroll
          for (int q = 0; q < 4; ++q) {
            unsigned u0 = __float_as_uint(v[2 * q]);
            unsigned u1 = __float_as_uint(v[2 * q + 1]);
            unsigned m0 = u0 & 0xffff0000u, m1 = u1 & 0xffff0000u;
            au[q] = (u0 >> 16) | m1;
            float l0 = v[2 * q] - __uint_as_float(m0);
            float l1 = v[2 * q + 1] - __uint_as_float(m1);
            lu[q] = (__float_as_uint(l0) >> 16) | (__float_as_uint(l1) & 0xffff0000u);
          }
          s8v ah = __builtin_bit_cast(s8v, au);
          s8v al = __builtin_bit_cast(s8v, lu);
#pragma unroll
          for (int gg = 0; gg < 3; ++gg)
            acc[mt][gg] = mfma3(ah, al, wh[gg][ks], wl[gg][ks], acc[mt][gg]);
        }
      }
      // issue next-step x loads (overlap barrier + other waves' work)
      const int tpre = (t + 1 < Tn) ? (t + 1) : (Tn - 1);
#pragma unroll
      for (int mt = 0; mt < 2; ++mt) {
        const int rowA = mq * 32 + mt * 16 + colr;
        const float* xq = x + ((size_t)rowA * Tn + tpre) * 512 + kh * 256 + kg * 8;
#pragma unroll
        for (int ks = 0; ks < 8; ++ks) {
          xp[mt][ks][0] = *(const float4*)(xq + ks * 32);
          xp[mt][ks][1] = *(const float4*)(xq + ks * 32 + 4);
        }
      }
    } else {
      // ---- h-side GEMM from packed u32 ring ----
      const unsigned* src;
      if (layer == 0)   src = h1ring + (size_t)((t - 1) & 3) * HS;  // h1[t-1] (t=0: zeros)
      else if (hs == 0) {
        // layer1 input side: wait for h1[t] available
        while (__hip_atomic_load(peerprog, __ATOMIC_RELAXED, __HIP_MEMORY_SCOPE_AGENT)
               < (unsigned)(t + 1))
          __builtin_amdgcn_s_sleep(1);
        __threadfence();
        src = h1ring + (size_t)(t & 3) * HS;                        // h1[t]
      } else            src = h2ring + (size_t)((t - 1) & 1) * HS;  // h2[t-1]

#pragma unroll
      for (int mt = 0; mt < 2; ++mt) {
        const int rowA = mq * 32 + mt * 16 + colr;
        const unsigned* pbase = src + (size_t)rowA * 512 + kh * 256 + kg * 8;
#pragma unroll
        for (int half = 0; half < 2; ++half) {
          u4v ub[8];
#pragma unroll
          for (int i = 0; i < 4; ++i) {
            const unsigned* pk = pbase + (half * 4 + i) * 32;
            ub[i * 2]     = *(const u4v*)(pk);
            ub[i * 2 + 1] = *(const u4v*)(pk + 4);
          }
#pragma unroll
          for (int i = 0; i < 4; ++i) {
            const int ks = half * 4 + i;
            u4v ahw, alw;
#pragma unroll
            for (int j = 0; j < 4; ++j) {
              unsigned a = (j < 2) ? ub[i * 2][2 * j] : ub[i * 2 + 1][2 * (j - 2)];
              unsigned b = (j < 2) ? ub[i * 2][2 * j + 1] : ub[i * 2 + 1][2 * (j - 2) + 1];
              ahw[j] = (a >> 16) | (b & 0xffff0000u);
              alw[j] = (a << 16 >> 16) | (b << 16);
            }
            s8v AH = __builtin_bit_cast(s8v, ahw);
            s8v AL = __builtin_bit_cast(s8v, alw);
#pragma unroll
            for (int gg = 0; gg < 3; ++gg)
              acc[mt][gg] = mfma3(AH, AL, wh[gg][ks], wl[gg][ks], acc[mt][gg]);
          }
        }
      }
    }

    // partial handoff: waves (hs0,kh0)->0, (hs0,kh1)->1, (hs1,kh1)->2
    const int widx = (hs == 0) ? kh : (kh == 1 ? 2 : -1);
    if (widx >= 0) {
#pragma unroll
      for (int mt = 0; mt < 2; ++mt)
#pragma unroll
        for (int gg = 0; gg < 3; ++gg)
#pragma unroll
          for (int r = 0; r < 4; ++r)
            part[widx][lane][mt * 12 + gg * 4 + r] = acc[mt][gg][r];
    }
    __syncthreads();

    // ---- epilogue: combine partials, gate math, publish h ----
    if (hs == 1 && kh == 0) {
      // layer0 back-pressure: don't overwrite h1 slot t&3 until layer1 did t-4
      if (layer == 0) {
        while (__hip_atomic_load(peerprog, __ATOMIC_RELAXED, __HIP_MEMORY_SCOPE_AGENT) + 3u
               < (unsigned)t)
          __builtin_amdgcn_s_sleep(1);
        __threadfence();
      }
      unsigned* od = layer ? (h2ring + (size_t)(t & 1) * HS)
                           : (h1ring + (size_t)(t & 3) * HS);
#pragma unroll
      for (int mt = 0; mt < 2; ++mt) {
#pragma unroll
        for (int r = 0; r < 4; ++r) {
          const int i0 = mt * 12 + r;
          float xr = part[0][lane][i0]     + part[1][lane][i0];
          float xz = part[0][lane][i0 + 4] + part[1][lane][i0 + 4];
          float xn = part[0][lane][i0 + 8] + part[1][lane][i0 + 8];
          float hr = acc[mt][0][r] + part[2][lane][i0];
          float hz = acc[mt][1][r] + part[2][lane][i0 + 4];
          float hn = acc[mt][2][r] + part[2][lane][i0 + 8];
          float rr = sigm(xr + hr + brz);
          float zz = sigm(xz + hz + bzz);
          float nn = tanh_f(xn + bin + rr * (hn + bhn));
          float h = (1.f - zz) * nn + zz * hown[mt][r];
          hown[mt][r] = h;
          const int row = mq * 32 + mt * 16 + kg * 4 + r;
          unsigned short hi = f2bf(h);
          unsigned pk = ((unsigned)hi << 16) | (unsigned)f2bf(h - bf2f(hi));
          od[(size_t)row * 512 + col] = pk;
          if (layer == 1 && t == Tn - 1) h2fin[(size_t)row * 512 + col] = h;
        }
      }
    }

    // -------- group barrier (32 blocks) + progress publish --------
    const bool do_bar = (layer == 0) || (t < Tn - 1);
    __syncthreads();
    if (do_bar && tid == 0) {
      __hip_atomic_fetch_add(mygc, 1u, __ATOMIC_RELEASE, __HIP_MEMORY_SCOPE_AGENT);
      const unsigned tgtv = 32u * (unsigned)(t + 1);
      while (__hip_atomic_load(mygc, __ATOMIC_RELAXED, __HIP_MEMORY_SCOPE_AGENT) < tgtv)
        __builtin_amdgcn_s_sleep(1);
      __threadfence();
      if (jg == 0)
        __hip_atomic_store(myprog, (unsigned)(t + 1), __ATOMIC_RELEASE,
                           __HIP_MEMORY_SCOPE_AGENT);
    }
    __syncthreads();
  }
}

// ---------- epilogue: out = h2_last @ Wfc^T + bfc ----------
__global__ __launch_bounds__(256) void fc_kernel(const float* __restrict__ h2,
                                                 const float* __restrict__ Wfc,
                                                 const float* __restrict__ bfc,
                                                 float* __restrict__ out) {
  int gid = blockIdx.x * 256 + threadIdx.x;  // 0..16383
  int b = gid >> 7, o = gid & 127;
  const float* hp = h2 + (size_t)b * Hn;
  const float* wp = Wfc + (size_t)o * Hn;
  float acc = bfc[o];
#pragma unroll 8
  for (int k = 0; k < Hn; k += 4) {
    float4 h = *(const float4*)(hp + k);
    float4 w = *(const float4*)(wp + k);
    acc = fmaf(h.x, w.x, acc); acc = fmaf(h.y, w.y, acc);
    acc = fmaf(h.z, w.z, acc); acc = fmaf(h.w, w.w, acc);
  }
  out[gid] = acc;
}

// ---------- epilogue: out_cate = out @ Wfcc^T + bfcc ----------
__global__ __launch_bounds__(256) void fcc_kernel(const float* __restrict__ outv,
                                                  const float* __restrict__ Wfcc,
                                                  const float* __restrict__ bfcc,
                                                  float* __restrict__ oc) {
  int gid = blockIdx.x * 256 + threadIdx.x;  // 0..49151
  int b = gid / 384, g = gid - b * 384;
  const float* op = outv + (size_t)b * 128;
  const float* wp = Wfcc + (size_t)g * 128;
  float acc = bfcc[g];
#pragma unroll 8
  for (int k = 0; k < 128; k += 4) {
    float4 o4 = *(const float4*)(op + k);
    float4 w4 = *(const float4*)(wp + k);
    acc = fmaf(o4.x, w4.x, acc); acc = fmaf(o4.y, w4.y, acc);
    acc = fmaf(o4.z, w4.z, acc); acc = fmaf(o4.w, w4.w, acc);
  }
  oc[gid] = acc;
}

extern "C" void kernel_launch(void* const* d_in, const int* in_sizes, int n_in,
                              void* d_out, int out_size, void* d_ws, size_t ws_size,
                              hipStream_t stream) {
  (void)in_sizes; (void)n_in; (void)out_size; (void)ws_size;
  const float* x    = (const float*)d_in[0];
  const float* Wih0 = (const float*)d_in[1];
  const float* Whh0 = (const float*)d_in[2];
  const float* bih0 = (const float*)d_in[3];
  const float* bhh0 = (const float*)d_in[4];
  const float* Wih1 = (const float*)d_in[5];
  const float* Whh1 = (const float*)d_in[6];
  const float* bih1 = (const float*)d_in[7];
  const float* bhh1 = (const float*)d_in[8];
  const float* Wfc  = (const float*)d_in[9];
  const float* bfc  = (const float*)d_in[10];
  const float* Wfcc = (const float*)d_in[11];
  const float* bfcc = (const float*)d_in[12];

  char* w = (char*)d_ws;
  unsigned* sync = (unsigned*)w;           // gcnt[8*32], l0prog[4*32], l1prog[4*32]
  unsigned* gcnt = sync;
  unsigned* l0prog = sync + 512;
  unsigned* l1prog = sync + 1024;
  unsigned* h1ring = (unsigned*)(w + 8192);        // 4 * 65536 u32 = 1 MB
  unsigned* h2ring = h1ring + 4 * HS;              // 2 * 65536 u32 = 512 KB
  float* h2fin = (float*)(h2ring + 2 * HS);        // 256 KB
  const size_t total = 8192 + (size_t)4 * HS * 4 + (size_t)2 * HS * 4 + (size_t)HS * 4;

  hipMemsetAsync(d_ws, 0, total, stream);

  gru_fused<<<NBLK, 256, 0, stream>>>(x, Wih0, Whh0, bih0, bhh0,
                                      Wih1, Whh1, bih1, bhh1,
                                      gcnt, l0prog, l1prog, h1ring, h2ring, h2fin);

  float* out = (float*)d_out;
  fc_kernel<<<64, 256, 0, stream>>>(h2fin, Wfc, bfc, out);
  fcc_kernel<<<192, 256, 0, stream>>>(out, Wfcc, bfcc, out + 16384);
}

// Round 6
// 9019.691 us; speedup vs baseline: 1.2168x; 1.2168x over previous
//
#include <hip/hip_runtime.h>

#define Tn 512
#define Hn 512
#define HS 65536           // u32 elements per h ring slot (128*512)
#define NBLK 256

typedef __attribute__((ext_vector_type(8))) short s8v;     // 8 bf16 (MFMA A/B frag)
typedef __attribute__((ext_vector_type(4))) float f4v;     // MFMA acc
typedef __attribute__((ext_vector_type(4))) unsigned u4v;

__device__ __forceinline__ unsigned short f2bf(float f) {  // RNE
  unsigned u = __float_as_uint(f);
  u = u + 0x7fffu + ((u >> 16) & 1u);
  return (unsigned short)(u >> 16);
}
__device__ __forceinline__ float bf2f(unsigned short s) {
  return __uint_as_float(((unsigned)s) << 16);
}
__device__ __forceinline__ float sigm(float v) { return 1.f / (1.f + __expf(-v)); }
__device__ __forceinline__ float tanh_f(float v) {
  v = fminf(fmaxf(v, -15.f), 15.f);
  float e = __expf(2.f * v);
  return (e - 1.f) / (e + 1.f);
}
__device__ __forceinline__ f4v mfma3(s8v ah, s8v al, s8v wh, s8v wl, f4v c) {
  c = __builtin_amdgcn_mfma_f32_16x16x32_bf16(ah, wh, c, 0, 0, 0);
  c = __builtin_amdgcn_mfma_f32_16x16x32_bf16(al, wh, c, 0, 0, 0);
  c = __builtin_amdgcn_mfma_f32_16x16x32_bf16(ah, wl, c, 0, 0, 0);
  return c;
}

// MALL-coherent (agent-scope, relaxed) accessors: lower to sc1 dword ops —
// cross-XCD coherent WITHOUT any buffer_wbl2/buffer_inv cache maintenance.
__device__ __forceinline__ unsigned ld_mall(const unsigned* p) {
  return __hip_atomic_load(p, __ATOMIC_RELAXED, __HIP_MEMORY_SCOPE_AGENT);
}
__device__ __forceinline__ void st_mall(unsigned* p, unsigned v) {
  __hip_atomic_store(p, v, __ATOMIC_RELAXED, __HIP_MEMORY_SCOPE_AGENT);
}

// ---------------- persistent fused 2-layer GRU, fence-free sync ----------------
// 256 blocks. g = bid&7 = mq*2+layer; jg = bid>>3 (16 cols).
// Group (layer,mq) = 32 jg-blocks sync via a 32-block group barrier with RELAXED
// atomics only. All cross-block data (h rings, progress) moves via sc1 (MALL)
// loads/stores; __syncthreads() per-wave vmcnt drain provides release ordering.
// h packed as u32 = (bf16_hi << 16) | bf16_lo.
// 4 waves/block: kh = wv&1 (K-half), hs = wv>>1 (0: input-side GEMM, 1: h GEMM).
// Weights bf16 hi/lo in VGPRs (192/wave), loaded once. x register-prefetched.
__global__ __launch_bounds__(256, 1) void gru_fused(
    const float* __restrict__ x,
    const float* __restrict__ Wih0, const float* __restrict__ Whh0,
    const float* __restrict__ bih0, const float* __restrict__ bhh0,
    const float* __restrict__ Wih1, const float* __restrict__ Whh1,
    const float* __restrict__ bih1, const float* __restrict__ bhh1,
    unsigned* __restrict__ gcnt,   // [8] stride 32 u32
    unsigned* __restrict__ l0prog, // [4] stride 32 u32
    unsigned* __restrict__ l1prog, // [4] stride 32 u32
    unsigned* __restrict__ h1ring, // 4 slots x 65536 u32
    unsigned* __restrict__ h2ring, // 2 slots x 65536 u32
    float* __restrict__ h2fin) {
  __shared__ float part[3][64][25];   // partial-acc handoff (stride 25: conflict-free)

  const int tid = threadIdx.x, lane = tid & 63, wv = tid >> 6;
  const int kh = wv & 1, hs = wv >> 1;
  const int colr = lane & 15, kg = lane >> 4;

  const int bid = blockIdx.x;
  const int g = bid & 7;
  const int layer = g & 1;
  const int mq = g >> 1;                   // row quarter (32 rows)
  const int jg = bid >> 3;                 // 0..31 column group
  const int col = jg * 16 + colr;

  // ---- load weight fragments (this wave's matrix + K-half) ----
  // B-frag: lane holds W[col][k = kh*256 + ks*32 + kg*8 + e]
  const float* W = (layer == 0) ? (hs ? Whh0 : Wih0) : (hs ? Whh1 : Wih1);
  s8v wh[3][8], wl[3][8];
#pragma unroll
  for (int gg = 0; gg < 3; ++gg) {
    const float* wrow = W + (size_t)(gg * Hn + col) * Hn + kh * 256 + kg * 8;
#pragma unroll
    for (int ks = 0; ks < 8; ++ks) {
#pragma unroll
      for (int e = 0; e < 8; ++e) {
        float v = wrow[ks * 32 + e];
        unsigned short hi = f2bf(v);
        wh[gg][ks][e] = (short)hi;
        wl[gg][ks][e] = (short)f2bf(v - bf2f(hi));
      }
    }
  }

  // biases: only the epilogue wave (hs==1, kh==0)
  float brz = 0, bzz = 0, bin = 0, bhn = 0;
  if (hs == 1 && kh == 0) {
    const float* bi = layer ? bih1 : bih0;
    const float* bb = layer ? bhh1 : bhh0;
    brz = bi[col] + bb[col];
    bzz = bi[Hn + col] + bb[Hn + col];
    bin = bi[2 * Hn + col];
    bhn = bb[2 * Hn + col];
  }

  const bool is_xw = (layer == 0 && hs == 0);   // x-prefetching wave

  // x prefetch registers: 2 mt x 8 ks x 2 float4
  float4 xp[2][8][2];
  if (is_xw) {
#pragma unroll
    for (int mt = 0; mt < 2; ++mt) {
      const int rowA = mq * 32 + mt * 16 + colr;
      const float* xq = x + ((size_t)rowA * Tn) * 512 + kh * 256 + kg * 8;  // t = 0
#pragma unroll
      for (int ks = 0; ks < 8; ++ks) {
        xp[mt][ks][0] = *(const float4*)(xq + ks * 32);
        xp[mt][ks][1] = *(const float4*)(xq + ks * 32 + 4);
      }
    }
  }

  unsigned* const mygc = gcnt + g * 32;
  unsigned* const myprog = (layer ? l1prog : l0prog) + mq * 32;
  const unsigned* const peerprog = (layer ? l0prog : l1prog) + mq * 32;

  float hown[2][4] = {{0.f, 0.f, 0.f, 0.f}, {0.f, 0.f, 0.f, 0.f}};

  for (int t = 0; t < Tn; ++t) {
    f4v acc[2][3];
#pragma unroll
    for (int mt = 0; mt < 2; ++mt)
#pragma unroll
      for (int gg = 0; gg < 3; ++gg) acc[mt][gg] = (f4v){0.f, 0.f, 0.f, 0.f};

    if (is_xw) {
      // ---- x-input GEMM from prefetched registers; hi/lo by truncation ----
#pragma unroll
      for (int mt = 0; mt < 2; ++mt) {
#pragma unroll
        for (int ks = 0; ks < 8; ++ks) {
          float v[8];
          v[0] = xp[mt][ks][0].x; v[1] = xp[mt][ks][0].y;
          v[2] = xp[mt][ks][0].z; v[3] = xp[mt][ks][0].w;
          v[4] = xp[mt][ks][1].x; v[5] = xp[mt][ks][1].y;
          v[6] = xp[mt][ks][1].z; v[7] = xp[mt][ks][1].w;
          u4v au, lu;
#pragma unroll
          for (int q = 0; q < 4; ++q) {
            unsigned u0 = __float_as_uint(v[2 * q]);
            unsigned u1 = __float_as_uint(v[2 * q + 1]);
            unsigned m0 = u0 & 0xffff0000u, m1 = u1 & 0xffff0000u;
            au[q] = (u0 >> 16) | m1;
            float l0 = v[2 * q] - __uint_as_float(m0);
            float l1 = v[2 * q + 1] - __uint_as_float(m1);
            lu[q] = (__float_as_uint(l0) >> 16) | (__float_as_uint(l1) & 0xffff0000u);
          }
          s8v ah = __builtin_bit_cast(s8v, au);
          s8v al = __builtin_bit_cast(s8v, lu);
#pragma unroll
          for (int gg = 0; gg < 3; ++gg)
            acc[mt][gg] = mfma3(ah, al, wh[gg][ks], wl[gg][ks], acc[mt][gg]);
        }
      }
      // issue next-step x loads (overlap barrier + other waves' work)
      const int tpre = (t + 1 < Tn) ? (t + 1) : (Tn - 1);
#pragma unroll
      for (int mt = 0; mt < 2; ++mt) {
        const int rowA = mq * 32 + mt * 16 + colr;
        const float* xq = x + ((size_t)rowA * Tn + tpre) * 512 + kh * 256 + kg * 8;
#pragma unroll
        for (int ks = 0; ks < 8; ++ks) {
          xp[mt][ks][0] = *(const float4*)(xq + ks * 32);
          xp[mt][ks][1] = *(const float4*)(xq + ks * 32 + 4);
        }
      }
    } else {
      // ---- h-side GEMM from packed u32 ring (sc1/MALL loads) ----
      const unsigned* src;
      if (layer == 0)   src = h1ring + (size_t)((t - 1) & 3) * HS;  // h1[t-1] (t=0: zeros)
      else if (hs == 0) {
        // layer1 input side: wait for h1[t] available
        while (ld_mall(peerprog) < (unsigned)(t + 1))
          __builtin_amdgcn_s_sleep(1);
        asm volatile("" ::: "memory");
        src = h1ring + (size_t)(t & 3) * HS;                        // h1[t]
      } else            src = h2ring + (size_t)((t - 1) & 1) * HS;  // h2[t-1]

#pragma unroll
      for (int mt = 0; mt < 2; ++mt) {
        const int rowA = mq * 32 + mt * 16 + colr;
        const unsigned* pbase = src + (size_t)rowA * 512 + kh * 256 + kg * 8;
#pragma unroll
        for (int ks = 0; ks < 8; ++ks) {
          unsigned u[8];
#pragma unroll
          for (int e = 0; e < 8; ++e) u[e] = ld_mall(pbase + ks * 32 + e);
          u4v ahw, alw;
#pragma unroll
          for (int j = 0; j < 4; ++j) {
            ahw[j] = (u[2 * j] >> 16) | (u[2 * j + 1] & 0xffff0000u);
            alw[j] = (u[2 * j] & 0xffffu) | (u[2 * j + 1] << 16);
          }
          s8v AH = __builtin_bit_cast(s8v, ahw);
          s8v AL = __builtin_bit_cast(s8v, alw);
#pragma unroll
          for (int gg = 0; gg < 3; ++gg)
            acc[mt][gg] = mfma3(AH, AL, wh[gg][ks], wl[gg][ks], acc[mt][gg]);
        }
      }
    }

    // partial handoff: waves (hs0,kh0)->0, (hs0,kh1)->1, (hs1,kh1)->2
    const int widx = (hs == 0) ? kh : (kh == 1 ? 2 : -1);
    if (widx >= 0) {
#pragma unroll
      for (int mt = 0; mt < 2; ++mt)
#pragma unroll
        for (int gg = 0; gg < 3; ++gg)
#pragma unroll
          for (int r = 0; r < 4; ++r)
            part[widx][lane][mt * 12 + gg * 4 + r] = acc[mt][gg][r];
    }
    __syncthreads();

    // ---- epilogue: combine partials, gate math, publish h (sc1 stores) ----
    if (hs == 1 && kh == 0) {
      // layer0 back-pressure: don't overwrite h1 slot t&3 until layer1 did t-4
      if (layer == 0) {
        while (ld_mall(peerprog) + 3u < (unsigned)t)
          __builtin_amdgcn_s_sleep(1);
        asm volatile("" ::: "memory");
      }
      unsigned* od = layer ? (h2ring + (size_t)(t & 1) * HS)
                           : (h1ring + (size_t)(t & 3) * HS);
#pragma unroll
      for (int mt = 0; mt < 2; ++mt) {
#pragma unroll
        for (int r = 0; r < 4; ++r) {
          const int i0 = mt * 12 + r;
          float xr = part[0][lane][i0]     + part[1][lane][i0];
          float xz = part[0][lane][i0 + 4] + part[1][lane][i0 + 4];
          float xn = part[0][lane][i0 + 8] + part[1][lane][i0 + 8];
          float hr = acc[mt][0][r] + part[2][lane][i0];
          float hz = acc[mt][1][r] + part[2][lane][i0 + 4];
          float hn = acc[mt][2][r] + part[2][lane][i0 + 8];
          float rr = sigm(xr + hr + brz);
          float zz = sigm(xz + hz + bzz);
          float nn = tanh_f(xn + bin + rr * (hn + bhn));
          float h = (1.f - zz) * nn + zz * hown[mt][r];
          hown[mt][r] = h;
          const int row = mq * 32 + mt * 16 + kg * 4 + r;
          unsigned short hi = f2bf(h);
          unsigned pk = ((unsigned)hi << 16) | (unsigned)f2bf(h - bf2f(hi));
          st_mall(od + (size_t)row * 512 + col, pk);
          if (layer == 1 && t == Tn - 1) h2fin[(size_t)row * 512 + col] = h;
        }
      }
    }

    // -------- group barrier (32 blocks), RELAXED atomics, no fences --------
    // __syncthreads() drains each wave's VMEM (incl. sc1 h-stores) before
    // tid0 signals arrival; readers use sc1 loads so no stale L2 copies.
    const bool do_bar = (layer == 0) || (t < Tn - 1);
    __syncthreads();
    if (do_bar && tid == 0) {
      asm volatile("" ::: "memory");
      __hip_atomic_fetch_add(mygc, 1u, __ATOMIC_RELAXED, __HIP_MEMORY_SCOPE_AGENT);
      const unsigned tgtv = 32u * (unsigned)(t + 1);
      while (ld_mall(mygc) < tgtv)
        __builtin_amdgcn_s_sleep(1);
      asm volatile("" ::: "memory");
      if (jg == 0)
        st_mall(myprog, (unsigned)(t + 1));
    }
    __syncthreads();
  }
}

// ---------- epilogue: out = h2_last @ Wfc^T + bfc ----------
__global__ __launch_bounds__(256) void fc_kernel(const float* __restrict__ h2,
                                                 const float* __restrict__ Wfc,
                                                 const float* __restrict__ bfc,
                                                 float* __restrict__ out) {
  int gid = blockIdx.x * 256 + threadIdx.x;  // 0..16383
  int b = gid >> 7, o = gid & 127;
  const float* hp = h2 + (size_t)b * Hn;
  const float* wp = Wfc + (size_t)o * Hn;
  float acc = bfc[o];
#pragma unroll 8
  for (int k = 0; k < Hn; k += 4) {
    float4 h = *(const float4*)(hp + k);
    float4 w = *(const float4*)(wp + k);
    acc = fmaf(h.x, w.x, acc); acc = fmaf(h.y, w.y, acc);
    acc = fmaf(h.z, w.z, acc); acc = fmaf(h.w, w.w, acc);
  }
  out[gid] = acc;
}

// ---------- epilogue: out_cate = out @ Wfcc^T + bfcc ----------
__global__ __launch_bounds__(256) void fcc_kernel(const float* __restrict__ outv,
                                                  const float* __restrict__ Wfcc,
                                                  const float* __restrict__ bfcc,
                                                  float* __restrict__ oc) {
  int gid = blockIdx.x * 256 + threadIdx.x;  // 0..49151
  int b = gid / 384, g = gid - b * 384;
  const float* op = outv + (size_t)b * 128;
  const float* wp = Wfcc + (size_t)g * 128;
  float acc = bfcc[g];
#pragma unroll 8
  for (int k = 0; k < 128; k += 4) {
    float4 o4 = *(const float4*)(op + k);
    float4 w4 = *(const float4*)(wp + k);
    acc = fmaf(o4.x, w4.x, acc); acc = fmaf(o4.y, w4.y, acc);
    acc = fmaf(o4.z, w4.z, acc); acc = fmaf(o4.w, w4.w, acc);
  }
  oc[gid] = acc;
}

extern "C" void kernel_launch(void* const* d_in, const int* in_sizes, int n_in,
                              void* d_out, int out_size, void* d_ws, size_t ws_size,
                              hipStream_t stream) {
  (void)in_sizes; (void)n_in; (void)out_size; (void)ws_size;
  const float* x    = (const float*)d_in[0];
  const float* Wih0 = (const float*)d_in[1];
  const float* Whh0 = (const float*)d_in[2];
  const float* bih0 = (const float*)d_in[3];
  const float* bhh0 = (const float*)d_in[4];
  const float* Wih1 = (const float*)d_in[5];
  const float* Whh1 = (const float*)d_in[6];
  const float* bih1 = (const float*)d_in[7];
  const float* bhh1 = (const float*)d_in[8];
  const float* Wfc  = (const float*)d_in[9];
  const float* bfc  = (const float*)d_in[10];
  const float* Wfcc = (const float*)d_in[11];
  const float* bfcc = (const float*)d_in[12];

  char* w = (char*)d_ws;
  unsigned* sync = (unsigned*)w;           // gcnt[8*32], l0prog[4*32], l1prog[4*32]
  unsigned* gcnt = sync;
  unsigned* l0prog = sync + 512;
  unsigned* l1prog = sync + 1024;
  unsigned* h1ring = (unsigned*)(w + 8192);        // 4 * 65536 u32 = 1 MB
  unsigned* h2ring = h1ring + 4 * HS;              // 2 * 65536 u32 = 512 KB
  float* h2fin = (float*)(h2ring + 2 * HS);        // 256 KB
  const size_t total = 8192 + (size_t)4 * HS * 4 + (size_t)2 * HS * 4 + (size_t)HS * 4;

  hipMemsetAsync(d_ws, 0, total, stream);

  gru_fused<<<NBLK, 256, 0, stream>>>(x, Wih0, Whh0, bih0, bhh0,
                                      Wih1, Whh1, bih1, bhh1,
                                      gcnt, l0prog, l1prog, h1ring, h2ring, h2fin);

  float* out = (float*)d_out;
  fc_kernel<<<64, 256, 0, stream>>>(h2fin, Wfc, bfc, out);
  fcc_kernel<<<192, 256, 0, stream>>>(out, Wfcc, bfcc, out + 16384);
}

// Round 7
// 5981.675 us; speedup vs baseline: 1.8348x; 1.5079x over previous
//
#include <hip/hip_runtime.h>

#define Tn 512
#define Hn 512
#define HS 65536           // u32 elements per h ring slot (128*512)
#define NBLK 256

typedef __attribute__((ext_vector_type(8))) short s8v;     // 8 bf16 (MFMA A/B frag)
typedef __attribute__((ext_vector_type(4))) float f4v;     // MFMA acc
typedef __attribute__((ext_vector_type(4))) unsigned u4v;

__device__ __forceinline__ unsigned short f2bf(float f) {  // RNE
  unsigned u = __float_as_uint(f);
  u = u + 0x7fffu + ((u >> 16) & 1u);
  return (unsigned short)(u >> 16);
}
__device__ __forceinline__ float bf2f(unsigned short s) {
  return __uint_as_float(((unsigned)s) << 16);
}
__device__ __forceinline__ float sigm(float v) { return 1.f / (1.f + __expf(-v)); }
__device__ __forceinline__ float tanh_f(float v) {
  v = fminf(fmaxf(v, -15.f), 15.f);
  float e = __expf(2.f * v);
  return (e - 1.f) / (e + 1.f);
}
__device__ __forceinline__ f4v mfma3(s8v ah, s8v al, s8v wh, s8v wl, f4v c) {
  c = __builtin_amdgcn_mfma_f32_16x16x32_bf16(ah, wh, c, 0, 0, 0);
  c = __builtin_amdgcn_mfma_f32_16x16x32_bf16(al, wh, c, 0, 0, 0);
  c = __builtin_amdgcn_mfma_f32_16x16x32_bf16(ah, wl, c, 0, 0, 0);
  return c;
}

// MALL-coherent (agent-scope, relaxed) accessors -> sc1 ops, no cache maintenance.
__device__ __forceinline__ unsigned ld_mall(const unsigned* p) {
  return __hip_atomic_load(p, __ATOMIC_RELAXED, __HIP_MEMORY_SCOPE_AGENT);
}
__device__ __forceinline__ unsigned long long ld_mall64(const unsigned long long* p) {
  return __hip_atomic_load(p, __ATOMIC_RELAXED, __HIP_MEMORY_SCOPE_AGENT);
}
__device__ __forceinline__ void st_mall(unsigned* p, unsigned v) {
  __hip_atomic_store(p, v, __ATOMIC_RELAXED, __HIP_MEMORY_SCOPE_AGENT);
}

// Dual-line flag poll: lanes 0..31 check lineA[lane] >= ta, lanes 32..63 check
// lineB[lane-32] >= tb. One vector load polls both conditions.
__device__ __forceinline__ void poll2(const int* pa, int ta, const int* pb2, int tb,
                                      int lane) {
  const int* p = (lane < 32) ? (pa + lane) : (pb2 + (lane - 32));
  const int tgt = (lane < 32) ? ta : tb;
  for (;;) {
    int v = (int)__hip_atomic_load(p, __ATOMIC_RELAXED, __HIP_MEMORY_SCOPE_AGENT);
    if (__all(v >= tgt)) break;
    __builtin_amdgcn_s_sleep(2);
  }
  asm volatile("" ::: "memory");   // no data loads hoisted above the poll
}

// ---------------- persistent fused 2-layer GRU, single-hop flag sync ----------------
// 256 blocks. g = bid&7 = mq*2+layer; jg = bid>>3 (16 cols). Group (layer,mq) =
// 32 jg-blocks; batch rows don't mix, so groups are closed except the l0->l1 h1
// handoff (ring depth 4, back-pressure) -- all ordering via per-block flags
// (flags[g][jg] = completed steps), sc1 data, in-wave vmcnt(0) release.
// 4 waves/block: kh = wv&1 (K-half), hs = wv>>1 (0: input-side GEMM, 1: h GEMM).
// Weights bf16 hi/lo in VGPRs (192/wave). x register-prefetched. One
// __syncthreads per step ('part' double-buffered by step parity).
__global__ __launch_bounds__(256, 1) void gru_fused(
    const float* __restrict__ x,
    const float* __restrict__ Wih0, const float* __restrict__ Whh0,
    const float* __restrict__ bih0, const float* __restrict__ bhh0,
    const float* __restrict__ Wih1, const float* __restrict__ Whh1,
    const float* __restrict__ bih1, const float* __restrict__ bhh1,
    int* __restrict__ flags,       // [8][32] int
    unsigned* __restrict__ h1ring, // 4 slots x 65536 u32
    unsigned* __restrict__ h2ring, // 2 slots x 65536 u32
    float* __restrict__ h2fin) {
  __shared__ float part[2][3][64][25];   // [parity][widx][lane][slot]

  const int tid = threadIdx.x, lane = tid & 63, wv = tid >> 6;
  const int kh = wv & 1, hs = wv >> 1;
  const int colr = lane & 15, kg = lane >> 4;

  const int bid = blockIdx.x;
  const int g = bid & 7;
  const int layer = g & 1;
  const int mq = g >> 1;                   // row quarter (32 rows)
  const int jg = bid >> 3;                 // 0..31 column group
  const int col = jg * 16 + colr;

  // ---- load weight fragments (this wave's matrix + K-half) ----
  const float* W = (layer == 0) ? (hs ? Whh0 : Wih0) : (hs ? Whh1 : Wih1);
  s8v wh[3][8], wl[3][8];
#pragma unroll
  for (int gg = 0; gg < 3; ++gg) {
    const float* wrow = W + (size_t)(gg * Hn + col) * Hn + kh * 256 + kg * 8;
#pragma unroll
    for (int ks = 0; ks < 8; ++ks) {
#pragma unroll
      for (int e = 0; e < 8; ++e) {
        float v = wrow[ks * 32 + e];
        unsigned short hi = f2bf(v);
        wh[gg][ks][e] = (short)hi;
        wl[gg][ks][e] = (short)f2bf(v - bf2f(hi));
      }
    }
  }

  // biases: only the epilogue wave (hs==1, kh==0)
  float brz = 0, bzz = 0, bin = 0, bhn = 0;
  if (hs == 1 && kh == 0) {
    const float* bi = layer ? bih1 : bih0;
    const float* bb = layer ? bhh1 : bhh0;
    brz = bi[col] + bb[col];
    bzz = bi[Hn + col] + bb[Hn + col];
    bin = bi[2 * Hn + col];
    bhn = bb[2 * Hn + col];
  }

  const bool is_xw = (layer == 0 && hs == 0);   // x-prefetching wave

  float4 xp[2][8][2];
  if (is_xw) {
#pragma unroll
    for (int mt = 0; mt < 2; ++mt) {
      const int rowA = mq * 32 + mt * 16 + colr;
      const float* xq = x + ((size_t)rowA * Tn) * 512 + kh * 256 + kg * 8;  // t = 0
#pragma unroll
      for (int ks = 0; ks < 8; ++ks) {
        xp[mt][ks][0] = *(const float4*)(xq + ks * 32);
        xp[mt][ks][1] = *(const float4*)(xq + ks * 32 + 4);
      }
    }
  }

  int* const ownline = flags + g * 32;
  int* const l0line = flags + (mq * 2) * 32;
  int* const l1line = flags + (mq * 2 + 1) * 32;

  float hown[2][4] = {{0.f, 0.f, 0.f, 0.f}, {0.f, 0.f, 0.f, 0.f}};

#pragma unroll 1
  for (int t = 0; t < Tn; ++t) {
    const int pb = t & 1;

    // ---- ordering polls (single-hop: flags ARE the barrier) ----
    if (hs == 1) {
      if (layer == 0) poll2(ownline, t, l1line, t - 3, lane);  // h1[t-1] ready + ring slot free
      else            poll2(ownline, t, ownline, t, lane);     // h2[t-1] ready
    } else if (layer == 1) {
      poll2(l0line, t + 1, l0line, t + 1, lane);               // h1[t] ready
    }

    f4v acc[2][3];
#pragma unroll
    for (int mt = 0; mt < 2; ++mt)
#pragma unroll
      for (int gg = 0; gg < 3; ++gg) acc[mt][gg] = (f4v){0.f, 0.f, 0.f, 0.f};

    if (is_xw) {
      // ---- x-input GEMM from prefetched registers; hi/lo by truncation ----
#pragma unroll
      for (int mt = 0; mt < 2; ++mt) {
#pragma unroll
        for (int ks = 0; ks < 8; ++ks) {
          float v[8];
          v[0] = xp[mt][ks][0].x; v[1] = xp[mt][ks][0].y;
          v[2] = xp[mt][ks][0].z; v[3] = xp[mt][ks][0].w;
          v[4] = xp[mt][ks][1].x; v[5] = xp[mt][ks][1].y;
          v[6] = xp[mt][ks][1].z; v[7] = xp[mt][ks][1].w;
          u4v au, lu;
#pragma unroll
          for (int q = 0; q < 4; ++q) {
            unsigned u0 = __float_as_uint(v[2 * q]);
            unsigned u1 = __float_as_uint(v[2 * q + 1]);
            unsigned m0 = u0 & 0xffff0000u, m1 = u1 & 0xffff0000u;
            au[q] = (u0 >> 16) | m1;
            float l0 = v[2 * q] - __uint_as_float(m0);
            float l1 = v[2 * q + 1] - __uint_as_float(m1);
            lu[q] = (__float_as_uint(l0) >> 16) | (__float_as_uint(l1) & 0xffff0000u);
          }
          s8v ah = __builtin_bit_cast(s8v, au);
          s8v al = __builtin_bit_cast(s8v, lu);
#pragma unroll
          for (int gg = 0; gg < 3; ++gg)
            acc[mt][gg] = mfma3(ah, al, wh[gg][ks], wl[gg][ks], acc[mt][gg]);
        }
      }
      // issue next-step x loads (overlap everything downstream)
      const int tpre = (t + 1 < Tn) ? (t + 1) : (Tn - 1);
#pragma unroll
      for (int mt = 0; mt < 2; ++mt) {
        const int rowA = mq * 32 + mt * 16 + colr;
        const float* xq = x + ((size_t)rowA * Tn + tpre) * 512 + kh * 256 + kg * 8;
#pragma unroll
        for (int ks = 0; ks < 8; ++ks) {
          xp[mt][ks][0] = *(const float4*)(xq + ks * 32);
          xp[mt][ks][1] = *(const float4*)(xq + ks * 32 + 4);
        }
      }
    } else {
      // ---- h-side GEMM: batched 64-bit sc1 loads, then unpack+MFMA ----
      const unsigned* src;
      if (layer == 0)   src = h1ring + (size_t)((t - 1) & 3) * HS;  // h1[t-1]
      else if (hs == 0) src = h1ring + (size_t)(t & 3) * HS;        // h1[t]
      else              src = h2ring + (size_t)((t - 1) & 1) * HS;  // h2[t-1]

#pragma unroll
      for (int mt = 0; mt < 2; ++mt) {
        const int rowA = mq * 32 + mt * 16 + colr;
        const unsigned long long* pb64 = (const unsigned long long*)
            (src + (size_t)rowA * 512 + kh * 256 + kg * 8);
        unsigned long long ub[32];
#pragma unroll
        for (int ks = 0; ks < 8; ++ks)
#pragma unroll
          for (int j = 0; j < 4; ++j)
            ub[ks * 4 + j] = ld_mall64(pb64 + ks * 16 + j);
#pragma unroll
        for (int ks = 0; ks < 8; ++ks) {
          u4v ahw, alw;
#pragma unroll
          for (int j = 0; j < 4; ++j) {
            unsigned a = (unsigned)ub[ks * 4 + j];
            unsigned b = (unsigned)(ub[ks * 4 + j] >> 32);
            ahw[j] = (a >> 16) | (b & 0xffff0000u);
            alw[j] = (a & 0xffffu) | (b << 16);
          }
          s8v AH = __builtin_bit_cast(s8v, ahw);
          s8v AL = __builtin_bit_cast(s8v, alw);
#pragma unroll
          for (int gg = 0; gg < 3; ++gg)
            acc[mt][gg] = mfma3(AH, AL, wh[gg][ks], wl[gg][ks], acc[mt][gg]);
        }
      }
    }

    // partial handoff: waves (hs0,kh0)->0, (hs0,kh1)->1, (hs1,kh1)->2
    const int widx = (hs == 0) ? kh : (kh == 1 ? 2 : -1);
    if (widx >= 0) {
#pragma unroll
      for (int mt = 0; mt < 2; ++mt)
#pragma unroll
        for (int gg = 0; gg < 3; ++gg)
#pragma unroll
          for (int r = 0; r < 4; ++r)
            part[pb][widx][lane][mt * 12 + gg * 4 + r] = acc[mt][gg][r];
    }
    __syncthreads();   // the ONLY barrier per step

    // ---- epilogue: combine, gates, publish h + flag (wave-local release) ----
    if (hs == 1 && kh == 0) {
      unsigned* od = layer ? (h2ring + (size_t)(t & 1) * HS)
                           : (h1ring + (size_t)(t & 3) * HS);
#pragma unroll
      for (int mt = 0; mt < 2; ++mt) {
#pragma unroll
        for (int r = 0; r < 4; ++r) {
          const int i0 = mt * 12 + r;
          float xr = part[pb][0][lane][i0]     + part[pb][1][lane][i0];
          float xz = part[pb][0][lane][i0 + 4] + part[pb][1][lane][i0 + 4];
          float xn = part[pb][0][lane][i0 + 8] + part[pb][1][lane][i0 + 8];
          float hr = acc[mt][0][r] + part[pb][2][lane][i0];
          float hz = acc[mt][1][r] + part[pb][2][lane][i0 + 4];
          float hn = acc[mt][2][r] + part[pb][2][lane][i0 + 8];
          float rr = sigm(xr + hr + brz);
          float zz = sigm(xz + hz + bzz);
          float nn = tanh_f(xn + bin + rr * (hn + bhn));
          float h = (1.f - zz) * nn + zz * hown[mt][r];
          hown[mt][r] = h;
          const int row = mq * 32 + mt * 16 + kg * 4 + r;
          unsigned short hi = f2bf(h);
          unsigned pk = ((unsigned)hi << 16) | (unsigned)f2bf(h - bf2f(hi));
          st_mall(od + (size_t)row * 512 + col, pk);
          if (layer == 1 && t == Tn - 1) h2fin[(size_t)row * 512 + col] = h;
        }
      }
      // release: drain h stores (this wave only), then publish flag
      asm volatile("s_waitcnt vmcnt(0)" ::: "memory");
      if (lane == 0)
        st_mall((unsigned*)(ownline + jg), (unsigned)(t + 1));
    }
  }
}

// ---------- epilogue: out = h2_last @ Wfc^T + bfc ----------
__global__ __launch_bounds__(256) void fc_kernel(const float* __restrict__ h2,
                                                 const float* __restrict__ Wfc,
                                                 const float* __restrict__ bfc,
                                                 float* __restrict__ out) {
  int gid = blockIdx.x * 256 + threadIdx.x;  // 0..16383
  int b = gid >> 7, o = gid & 127;
  const float* hp = h2 + (size_t)b * Hn;
  const float* wp = Wfc + (size_t)o * Hn;
  float acc = bfc[o];
#pragma unroll 8
  for (int k = 0; k < Hn; k += 4) {
    float4 h = *(const float4*)(hp + k);
    float4 w = *(const float4*)(wp + k);
    acc = fmaf(h.x, w.x, acc); acc = fmaf(h.y, w.y, acc);
    acc = fmaf(h.z, w.z, acc); acc = fmaf(h.w, w.w, acc);
  }
  out[gid] = acc;
}

// ---------- epilogue: out_cate = out @ Wfcc^T + bfcc ----------
__global__ __launch_bounds__(256) void fcc_kernel(const float* __restrict__ outv,
                                                  const float* __restrict__ Wfcc,
                                                  const float* __restrict__ bfcc,
                                                  float* __restrict__ oc) {
  int gid = blockIdx.x * 256 + threadIdx.x;  // 0..49151
  int b = gid / 384, g = gid - b * 384;
  const float* op = outv + (size_t)b * 128;
  const float* wp = Wfcc + (size_t)g * 128;
  float acc = bfcc[g];
#pragma unroll 8
  for (int k = 0; k < 128; k += 4) {
    float4 o4 = *(const float4*)(op + k);
    float4 w4 = *(const float4*)(wp + k);
    acc = fmaf(o4.x, w4.x, acc); acc = fmaf(o4.y, w4.y, acc);
    acc = fmaf(o4.z, w4.z, acc); acc = fmaf(o4.w, w4.w, acc);
  }
  oc[gid] = acc;
}

extern "C" void kernel_launch(void* const* d_in, const int* in_sizes, int n_in,
                              void* d_out, int out_size, void* d_ws, size_t ws_size,
                              hipStream_t stream) {
  (void)in_sizes; (void)n_in; (void)out_size; (void)ws_size;
  const float* x    = (const float*)d_in[0];
  const float* Wih0 = (const float*)d_in[1];
  const float* Whh0 = (const float*)d_in[2];
  const float* bih0 = (const float*)d_in[3];
  const float* bhh0 = (const float*)d_in[4];
  const float* Wih1 = (const float*)d_in[5];
  const float* Whh1 = (const float*)d_in[6];
  const float* bih1 = (const float*)d_in[7];
  const float* bhh1 = (const float*)d_in[8];
  const float* Wfc  = (const float*)d_in[9];
  const float* bfc  = (const float*)d_in[10];
  const float* Wfcc = (const float*)d_in[11];
  const float* bfcc = (const float*)d_in[12];

  char* w = (char*)d_ws;
  int* flags = (int*)w;                            // [8][32] int, 1 KB
  unsigned* h1ring = (unsigned*)(w + 8192);        // 4 * 65536 u32 = 1 MB
  unsigned* h2ring = h1ring + 4 * HS;              // 2 * 65536 u32 = 512 KB
  float* h2fin = (float*)(h2ring + 2 * HS);        // 256 KB
  const size_t total = 8192 + (size_t)4 * HS * 4 + (size_t)2 * HS * 4 + (size_t)HS * 4;

  hipMemsetAsync(d_ws, 0, total, stream);

  gru_fused<<<NBLK, 256, 0, stream>>>(x, Wih0, Whh0, bih0, bhh0,
                                      Wih1, Whh1, bih1, bhh1,
                                      flags, h1ring, h2ring, h2fin);

  float* out = (float*)d_out;
  fc_kernel<<<64, 256, 0, stream>>>(h2fin, Wfc, bfc, out);
  fcc_kernel<<<192, 256, 0, stream>>>(out, Wfcc, bfcc, out + 16384);
}